// Round 2
// baseline (4339.491 us; speedup 1.0000x reference)
//
#include <hip/hip_runtime.h>
#include <math.h>

#define DIMH 84
#define WDIM 1184
#define BM 32

// ---------------- path / irrep constant tables ----------------
// IRR_H = [(16,0,+),(8,1,-),(8,1,+),(4,2,+)]  slices 0,16,40,64  dims 16,24,24,20
// IRR_E = [(1,0,+),(1,1,-),(1,2,+)]           slices 0,1,4
// 17 paths, W_DIM=1184. cidx -> mv {16,8,8,4}, d3 {1,3,3,5}, outoff {0,16,40,64}
struct PathC { int key, woff, mu, cidx, d1, d2, d3, sla, slb; };
__constant__ PathC PC[17] = {
  {0, 0,    16, 0, 1,1,1, 0, 0},   // (0,0,0)
  {1, 256,  16, 1, 1,3,3, 0, 1},   // (0,1,1)
  {2, 384,  16, 3, 1,5,5, 0, 4},   // (0,2,3)
  {3, 448,  8,  1, 3,1,3, 16,0},   // (1,0,1)
  {4, 512,  8,  0, 3,3,1, 16,1},   // (1,1,0)
  {5, 640,  8,  2, 3,3,3, 16,1},   // (1,1,2)
  {6, 704,  8,  3, 3,3,5, 16,1},   // (1,1,3)
  {7, 736,  8,  1, 3,5,3, 16,4},   // (1,2,1)
  {3, 800,  8,  2, 3,1,3, 40,0},   // (2,0,2)
  {5, 864,  8,  1, 3,3,3, 40,1},   // (2,1,1)
  {7, 928,  8,  2, 3,5,3, 40,4},   // (2,2,2)
  {8, 992,  8,  3, 3,5,5, 40,4},   // (2,2,3)
  {9, 1024, 4,  3, 5,1,5, 64,0},   // (3,0,3)
  {10,1040, 4,  1, 5,3,3, 64,1},   // (3,1,1)
  {11,1072, 4,  0, 5,5,1, 64,4},   // (3,2,0)
  {12,1136, 4,  2, 5,5,3, 64,4},   // (3,2,2)
  {13,1168, 4,  3, 5,5,5, 64,4},   // (3,2,3)
};
__constant__ int MV4[4]   = {16, 8, 8, 4};
// fan per output irrep: 28, 44, 28, 40
__constant__ float FANS[4] = {0.18898223650461363f, 0.15075567228888181f,
                              0.18898223650461363f, 0.15811388300841897f};
// unique (l1,l2,l3) keys for wigner3j
__constant__ int KL[14][3] = {{0,0,0},{0,1,1},{0,2,2},{1,0,1},{1,1,0},{1,1,1},{1,1,2},
                              {1,2,1},{1,2,2},{2,0,2},{2,1,1},{2,2,0},{2,2,1},{2,2,2}};

// ---------------- on-device Wigner 3j (exact replica of reference) ----------------
__device__ double dfact(int n){ double r=1.0; for(int i=2;i<=n;++i) r*=(double)i; return r; }

__device__ double cg_coef(int j1,int m1,int j2,int m2,int j3,int m3){
  if (m1+m2 != m3) return 0.0;
  int kmin = max(0, max(j2-j3-m1, j1-j3+m2));
  int kmax = min(j1+j2-j3, min(j1-m1, j2+m2));
  if (kmax < kmin) return 0.0;
  double pref = sqrt((2.0*j3+1.0)*dfact(j3+j1-j2)*dfact(j3-j1+j2)*dfact(j1+j2-j3)/dfact(j1+j2+j3+1));
  pref *= sqrt(dfact(j3+m3)*dfact(j3-m3)*dfact(j1-m1)*dfact(j1+m1)*dfact(j2-m2)*dfact(j2+m2));
  double s = 0.0;
  for (int k=kmin;k<=kmax;++k){
    double d = dfact(k)*dfact(j1+j2-j3-k)*dfact(j1-m1-k)*dfact(j2+m2-k)*dfact(j3-j2+m1+k)*dfact(j3-j1-m2+k);
    s += ((k&1)? -1.0:1.0)/d;
  }
  return pref*s;
}

__device__ void buildQ(int l, double qr[5][5], double qi[5][5]){
  const double is2 = 0.70710678118654752440;
  for (int a=0;a<5;++a) for(int b=0;b<5;++b){ qr[a][b]=0.0; qi[a][b]=0.0; }
  for (int m=-l; m<0; ++m){
    qr[l+m][l-m] = is2;      // q[l+m, l+|m|] = 1/sqrt2
    qi[l+m][l+m] = -is2;     // q[l+m, l-|m|] = -i/sqrt2
  }
  qr[l][l] = 1.0;
  for (int m=1; m<=l; ++m){
    double sgn = (m & 1) ? -1.0 : 1.0;
    qr[l+m][l+m] = sgn*is2;
    qi[l+m][l-m] = sgn*is2;  // i*(-1)^m/sqrt2
  }
  if (l == 1) {              // multiply by (-i)^1
    for (int a=0;a<5;++a) for(int b=0;b<5;++b){ double r=qr[a][b], im=qi[a][b]; qr[a][b]=im; qi[a][b]=-r; }
  } else if (l == 2) {       // (-i)^2 = -1
    for (int a=0;a<5;++a) for(int b=0;b<5;++b){ qr[a][b]=-qr[a][b]; qi[a][b]=-qi[a][b]; }
  }
}

__global__ void w3j_kernel(float* __restrict__ w3j) {
  int kid = threadIdx.x;
  if (kid >= 14) return;
  int l1 = KL[kid][0], l2 = KL[kid][1], l3 = KL[kid][2];
  int d1 = 2*l1+1, d2 = 2*l2+1, d3 = 2*l3+1;
  double C[5][5][5];
  for (int a=0;a<d1;++a) for (int b=0;b<d2;++b) for (int c=0;c<d3;++c) C[a][b][c]=0.0;
  for (int a=0;a<d1;++a) for (int b=0;b<d2;++b) {
    int m1 = a-l1, m2 = b-l2, m3 = m1+m2;
    if (m3 >= -l3 && m3 <= l3) C[a][b][l3+m3] = cg_coef(l1,m1,l2,m2,l3,m3);
  }
  double q1r[5][5],q1i[5][5],q2r[5][5],q2i[5][5],q3r[5][5],q3i[5][5];
  buildQ(l1,q1r,q1i); buildQ(l2,q2r,q2i); buildQ(l3,q3r,q3i);
  double Rr[5][5][5], Ri[5][5][5];
  double sre = 0.0, sim = 0.0;
  for (int i=0;i<d1;++i) for (int j=0;j<d2;++j) for (int k=0;k<d3;++k) {
    double ar=0.0, ai=0.0;
    for (int a=0;a<d1;++a) for (int b=0;b<d2;++b) for (int c=0;c<d3;++c) {
      double cv = C[a][b][c];
      if (cv == 0.0) continue;
      double tr = q1r[a][i]*q2r[b][j] - q1i[a][i]*q2i[b][j];
      double ti = q1r[a][i]*q2i[b][j] + q1i[a][i]*q2r[b][j];
      double ur = tr*q3r[c][k] + ti*q3i[c][k];   // * conj(q3)
      double ui = ti*q3r[c][k] - tr*q3i[c][k];
      ar += ur*cv; ai += ui*cv;
    }
    Rr[i][j][k]=ar; Ri[i][j][k]=ai;
    sre += fabs(ar); sim += fabs(ai);
  }
  bool use_re = (sre > sim);
  double nrm = 0.0;
  for (int i=0;i<d1;++i) for (int j=0;j<d2;++j) for (int k=0;k<d3;++k) {
    double v = use_re ? Rr[i][j][k] : Ri[i][j][k]; nrm += v*v;
  }
  double inv = 1.0/sqrt(nrm);
  for (int i=0;i<d1;++i) for (int j=0;j<d2;++j) for (int k=0;k<d3;++k) {
    double v = use_re ? Rr[i][j][k] : Ri[i][j][k];
    w3j[kid*125 + (i*d2+j)*d3 + k] = (float)(v*inv);
  }
}

// ---------------- W2 transpose: W2T[col][h] = W2[h][col] ----------------
__global__ void w2t_kernel(const float* __restrict__ W2, float* __restrict__ W2T) {
  int idx = blockIdx.x*256 + threadIdx.x;
  if (idx < 64*WDIM) {
    int c = idx >> 6, h = idx & 63;
    W2T[idx] = W2[h*WDIM + c];
  }
}

// ---------------- fused radial-MLP + tensor-product + scatter ----------------
// block = 256 threads, 32 edges. thread = (e = t>>3, slot = t&7).
// Invariant: paths into c0 all have mv=16 (v = slot, slot+8); c1,c2 mv=8 (v=slot);
// c3 mv=4 (v=slot, slots>=4 idle) -> each thread statically owns 13 output floats.
__global__ __launch_bounds__(256, 2) void edge_kernel(
  const float* __restrict__ x, const int* __restrict__ eidx,
  const float* __restrict__ shg, const float* __restrict__ rbf,
  const float* __restrict__ W1, const float* __restrict__ b1,
  const float* __restrict__ W2T, const float* __restrict__ b2,
  const float* __restrict__ w3j, float* __restrict__ m_i, int E)
{
  __shared__ float s_act[BM][68];   // pad 68: conflict-free broadcast reads
  __shared__ float s_w2[64][68];    // staged W2T chunk [col][h]
  __shared__ float s_xj[BM][84];
  __shared__ float s_sh[BM][12];
  __shared__ float s_tmp[BM][81];   // pad 81: conflict-free
  int t = threadIdx.x;
  int e0 = blockIdx.x * BM;

  for (int idx = t; idx < BM*84; idx += 256) {
    int e = idx/84, d = idx - e*84;
    int ge = e0 + e;
    int j = (ge < E) ? eidx[E + ge] : 0;       // edge_index[1] = source
    s_xj[e][d] = x[j*84 + d];
  }
  for (int idx = t; idx < BM*9; idx += 256) {
    int e = idx/9, d = idx - e*9;
    int ge = min(e0 + e, E-1);
    s_sh[e][d] = shg[ge*9 + d];
  }
  for (int idx = t; idx < BM*64; idx += 256) {
    int e = idx >> 6, h = idx & 63;
    int ge = min(e0 + e, E-1);
    float s = b1[h];
    const float* r = rbf + ge*16;
    #pragma unroll
    for (int q = 0; q < 16; ++q) s = fmaf(r[q], W1[q*64 + h], s);
    s_act[e][h] = s / (1.f + expf(-s));        // silu
  }
  __syncthreads();

  int e = t >> 3, slot = t & 7;
  float a_reg[64];
  #pragma unroll
  for (int h4 = 0; h4 < 16; ++h4) {
    float4 v = *(const float4*)&s_act[e][h4*4];
    a_reg[h4*4+0]=v.x; a_reg[h4*4+1]=v.y; a_reg[h4*4+2]=v.z; a_reg[h4*4+3]=v.w;
  }
  float o0[2] = {0.f,0.f};
  float o1[3] = {0.f,0.f,0.f};
  float o2[3] = {0.f,0.f,0.f};
  float o3[5] = {0.f,0.f,0.f,0.f,0.f};

  for (int p = 0; p < 17; ++p) {
    PathC P = PC[p];
    int mv = MV4[P.cidx], d3 = P.d3;
    __syncthreads();   // prev path's readers done before tmp overwrite
    int md = P.mu * d3;
    for (int idx = t; idx < BM*md; idx += 256) {
      int ee = idx / md, r = idx - ee*md;
      int u = r / d3, kk = r - u*d3;
      const float* cg = w3j + P.key*125 + kk;
      float s = 0.f;
      for (int i = 0; i < P.d1; ++i) {
        float xa = s_xj[ee][P.sla + u*P.d1 + i];
        for (int jj = 0; jj < P.d2; ++jj)
          s = fmaf(xa * s_sh[ee][P.slb + jj], cg[(i*P.d2 + jj)*d3], s);
      }
      s_tmp[ee][r] = s;
    }
    int ncol_full = P.mu * mv;
    int CH = (ncol_full < 64) ? ncol_full : 64;
    int ucp = CH / mv;
    for (int u0 = 0; u0 < P.mu; u0 += ucp) {
      __syncthreads();  // prev chunk readers done; tmp writes visible after next sync
      for (int idx = t; idx < CH*64; idx += 256) {
        int c = idx >> 6, h = idx & 63;
        s_w2[c][h] = W2T[(P.woff + u0*mv + c)*64 + h];
      }
      __syncthreads();
      for (int uu = 0; uu < ucp; ++uu) {
        int u = u0 + uu;
        int vcount = (P.cidx == 0) ? 2 : 1;
        for (int vr = 0; vr < vcount; ++vr) {
          int v = slot + vr*8;
          if (v < mv) {
            int c = uu*mv + v;
            float wv = b2[P.woff + u*mv + v];
            #pragma unroll
            for (int h4 = 0; h4 < 16; ++h4) {
              float4 w4 = *(const float4*)&s_w2[c][h4*4];
              wv = fmaf(a_reg[h4*4+0], w4.x, wv);
              wv = fmaf(a_reg[h4*4+1], w4.y, wv);
              wv = fmaf(a_reg[h4*4+2], w4.z, wv);
              wv = fmaf(a_reg[h4*4+3], w4.w, wv);
            }
            const float* tp = &s_tmp[e][u*d3];
            if (P.cidx == 0) {
              o0[vr] = fmaf(tp[0], wv, o0[vr]);
            } else if (P.cidx == 1) {
              o1[0] = fmaf(tp[0], wv, o1[0]);
              o1[1] = fmaf(tp[1], wv, o1[1]);
              o1[2] = fmaf(tp[2], wv, o1[2]);
            } else if (P.cidx == 2) {
              o2[0] = fmaf(tp[0], wv, o2[0]);
              o2[1] = fmaf(tp[1], wv, o2[1]);
              o2[2] = fmaf(tp[2], wv, o2[2]);
            } else {
              #pragma unroll
              for (int kk = 0; kk < 5; ++kk) o3[kk] = fmaf(tp[kk], wv, o3[kk]);
            }
          }
        }
      }
    }
  }

  int ge = e0 + e;
  if (ge < E) {
    int ni = eidx[ge];                 // edge_index[0] = destination
    float* mrow = m_i + ni*84;
    atomicAdd(&mrow[slot],      o0[0]*FANS[0]);
    atomicAdd(&mrow[slot + 8],  o0[1]*FANS[0]);
    #pragma unroll
    for (int kk = 0; kk < 3; ++kk) atomicAdd(&mrow[16 + slot*3 + kk], o1[kk]*FANS[1]);
    #pragma unroll
    for (int kk = 0; kk < 3; ++kk) atomicAdd(&mrow[40 + slot*3 + kk], o2[kk]*FANS[2]);
    if (slot < 4) {
      #pragma unroll
      for (int kk = 0; kk < 5; ++kk) atomicAdd(&mrow[64 + slot*5 + kk], o3[kk]*FANS[3]);
    }
  }
}

// ---------------- block-diagonal o3_linear helpers ----------------
__device__ float o3lin_hh(const float* v, const float* w, int d) {
  float s = 0.f;
  if (d < 16) {
    #pragma unroll
    for (int u = 0; u < 16; ++u) s = fmaf(v[u], w[u*16 + d], s);
    return s * 0.25f;
  } else if (d < 40) {
    int loc = d-16, vv = loc/3, kk = loc - vv*3;
    #pragma unroll
    for (int u = 0; u < 8; ++u) s = fmaf(v[16 + u*3 + kk], w[256 + u*8 + vv], s);
    return s * 0.35355339059327373f;
  } else if (d < 64) {
    int loc = d-40, vv = loc/3, kk = loc - vv*3;
    #pragma unroll
    for (int u = 0; u < 8; ++u) s = fmaf(v[40 + u*3 + kk], w[320 + u*8 + vv], s);
    return s * 0.35355339059327373f;
  } else {
    int loc = d-64, vv = loc/5, kk = loc - vv*5;
    #pragma unroll
    for (int u = 0; u < 4; ++u) s = fmaf(v[64 + u*5 + kk], w[384 + u*4 + vv], s);
    return s * 0.5f;
  }
}

__device__ float o3lin_pre(const float* v, const float* w, int d) {
  float s = 0.f;
  if (d < 16) {
    #pragma unroll
    for (int u = 0; u < 16; ++u) s = fmaf(v[u], w[u*16 + d], s);
    return s * 0.25f;
  } else if (d < 36) {
    int vv = d - 16;
    #pragma unroll
    for (int u = 0; u < 16; ++u) s = fmaf(v[u], w[256 + u*20 + vv], s);
    return s * 0.25f;
  } else if (d < 60) {
    int loc = d-36, vv = loc/3, kk = loc - vv*3;
    #pragma unroll
    for (int u = 0; u < 8; ++u) s = fmaf(v[16 + u*3 + kk], w[576 + u*8 + vv], s);
    return s * 0.35355339059327373f;
  } else if (d < 84) {
    int loc = d-60, vv = loc/3, kk = loc - vv*3;
    #pragma unroll
    for (int u = 0; u < 8; ++u) s = fmaf(v[40 + u*3 + kk], w[640 + u*8 + vv], s);
    return s * 0.35355339059327373f;
  } else {
    int loc = d-84, vv = loc/5, kk = loc - vv*5;
    #pragma unroll
    for (int u = 0; u < 4; ++u) s = fmaf(v[64 + u*5 + kk], w[704 + u*4 + vv], s);
    return s * 0.5f;
  }
}

// ---------------- h1 = x + lin_res(m_i); accumulate bn stats ----------------
__global__ __launch_bounds__(256) void node_res_kernel(
  const float* __restrict__ x, const float* __restrict__ m_i,
  const float* __restrict__ lw, float* __restrict__ h1,
  float* __restrict__ stats, int N)
{
  __shared__ float s_m[4][84];
  __shared__ float s_sum[16];
  __shared__ float s_sq[36];
  int t = threadIdx.x;
  int n0 = blockIdx.x*4;
  if (t < 16) s_sum[t] = 0.f;
  if (t < 36) s_sq[t] = 0.f;
  for (int idx = t; idx < 4*84; idx += 256) {
    int e = idx/84, d = idx - e*84;
    int n = n0 + e;
    s_m[e][d] = (n < N) ? m_i[n*84 + d] : 0.f;
  }
  __syncthreads();
  int w = t >> 6, lane = t & 63;
  int n = n0 + w;
  for (int rep = 0; rep < 2; ++rep) {
    int d = lane + rep*64;
    if (d < 84 && n < N) {
      float v = x[n*84 + d] + o3lin_hh(s_m[w], lw, d);
      h1[n*84 + d] = v;
      if (d < 16) {
        atomicAdd(&s_sum[d], v);
        atomicAdd(&s_sq[d], v*v);
      } else {
        int ch = (d < 40) ? 16 + (d-16)/3 : (d < 64) ? 24 + (d-40)/3 : 32 + (d-64)/5;
        atomicAdd(&s_sq[ch], v*v);
      }
    }
  }
  __syncthreads();
  if (t < 16) atomicAdd(&stats[t], s_sum[t]);
  if (t < 36) atomicAdd(&stats[16 + t], s_sq[t]);
}

// ---------------- batchnorm finalize: scale/shift per channel ----------------
__global__ void bn_finalize_kernel(const float* __restrict__ stats,
                                   const float* __restrict__ bnw,
                                   const float* __restrict__ bnb,
                                   float* __restrict__ scsh, int N)
{
  int t = threadIdx.x;
  if (t >= 36) return;
  float q = stats[16 + t];
  float scale, shift = 0.f;
  if (t < 16) {
    float mean = stats[t] / (float)N;
    float var  = q / (float)N - mean*mean;        // E[(f-mean)^2]
    scale = bnw[t] / sqrtf(var + 1e-5f);
    shift = bnb[t] - mean*scale;
  } else {
    float dd = (t < 32) ? 3.f : 5.f;
    float var = q / ((float)N * dd);
    scale = bnw[t] / sqrtf(var + 1e-5f);
  }
  scsh[t] = scale;
  scsh[36 + t] = shift;
}

// ---------------- bn apply + pre_gate + gate + post_gate ----------------
__global__ __launch_bounds__(256) void node_out_kernel(
  const float* __restrict__ h1, const float* __restrict__ scsh,
  const float* __restrict__ wpre, const float* __restrict__ wpost,
  float* __restrict__ out, int N)
{
  __shared__ float s_y[4][84];
  __shared__ float s_p[4][104];
  __shared__ float s_g[4][84];
  int t = threadIdx.x;
  int n0 = blockIdx.x*4;
  for (int idx = t; idx < 4*84; idx += 256) {
    int e = idx/84, d = idx - e*84;
    int n = n0 + e;
    float v = (n < N) ? h1[n*84 + d] : 0.f;
    int ch = (d < 16) ? d : (d < 40) ? 16 + (d-16)/3 : (d < 64) ? 24 + (d-40)/3 : 32 + (d-64)/5;
    s_y[e][d] = v*scsh[ch] + scsh[36 + ch];
  }
  __syncthreads();
  int w = t >> 6, lane = t & 63;
  for (int rep = 0; rep < 2; ++rep) {
    int d = lane + rep*64;
    if (d < 104) s_p[w][d] = o3lin_pre(s_y[w], wpre, d);
  }
  __syncthreads();
  for (int rep = 0; rep < 2; ++rep) {
    int d = lane + rep*64;
    if (d < 84) {
      float v;
      if (d < 16)      { float sv = s_p[w][d]; v = sv / (1.f + expf(-sv)); }
      else if (d < 40) { int loc = d-16; v = s_p[w][36 + loc] / (1.f + expf(-s_p[w][16 + loc/3])); }
      else if (d < 64) { int loc = d-40; v = s_p[w][60 + loc] / (1.f + expf(-s_p[w][24 + loc/3])); }
      else             { int loc = d-64; v = s_p[w][84 + loc] / (1.f + expf(-s_p[w][32 + loc/5])); }
      s_g[w][d] = v;
    }
  }
  __syncthreads();
  int n = n0 + w;
  for (int rep = 0; rep < 2; ++rep) {
    int d = lane + rep*64;
    if (d < 84 && n < N) out[n*84 + d] = o3lin_hh(s_g[w], wpost, d);
  }
}

// ---------------- launch ----------------
extern "C" void kernel_launch(void* const* d_in, const int* in_sizes, int n_in,
                              void* d_out, int out_size, void* d_ws, size_t ws_size,
                              hipStream_t stream)
{
  const float* x    = (const float*)d_in[0];
  const int*   eidx = (const int*)d_in[1];
  const float* shg  = (const float*)d_in[2];
  const float* rbf  = (const float*)d_in[3];
  const float* W1   = (const float*)d_in[4];
  const float* b1   = (const float*)d_in[5];
  const float* W2   = (const float*)d_in[6];
  const float* b2   = (const float*)d_in[7];
  const float* lrw  = (const float*)d_in[8];
  const float* prw  = (const float*)d_in[9];
  const float* pgw  = (const float*)d_in[10];
  const float* bnw  = (const float*)d_in[11];
  const float* bnb  = (const float*)d_in[12];
  int N = in_sizes[0] / 84;
  int E = in_sizes[1] / 2;

  // ws layout (floats): m_i[N*84] | stats[64] | scsh[80] | h1[N*84] | w3j[1750] | W2T[75776]
  float* ws    = (float*)d_ws;
  float* m_i   = ws;
  float* stats = ws + (size_t)N*84;
  float* scsh  = stats + 64;
  float* h1    = scsh + 80;
  float* w3j   = h1 + (size_t)N*84;
  float* W2T   = w3j + 14*125;
  // total ~1.76M floats (~7 MB)

  hipMemsetAsync(m_i, 0, ((size_t)N*84 + 64)*sizeof(float), stream);
  w3j_kernel<<<1, 64, 0, stream>>>(w3j);
  w2t_kernel<<<(64*WDIM + 255)/256, 256, 0, stream>>>(W2, W2T);
  edge_kernel<<<(E + BM - 1)/BM, 256, 0, stream>>>(x, eidx, shg, rbf, W1, b1, W2T, b2, w3j, m_i, E);
  node_res_kernel<<<(N + 3)/4, 256, 0, stream>>>(x, m_i, lrw, h1, stats, N);
  bn_finalize_kernel<<<1, 64, 0, stream>>>(stats, bnw, bnb, scsh, N);
  node_out_kernel<<<(N + 3)/4, 256, 0, stream>>>(h1, scsh, prw, pgw, (float*)d_out, N);
}

// Round 3
// 1358.274 us; speedup vs baseline: 3.1949x; 3.1949x over previous
//
#include <hip/hip_runtime.h>
#include <math.h>

#define DIMH 84
#define WDIM 1184
#define BM 32

// ---------------- path / irrep constant tables ----------------
// IRR_H = [(16,0,+),(8,1,-),(8,1,+),(4,2,+)]  slices 0,16,40,64  dims 16,24,24,20
// IRR_E = [(1,0,+),(1,1,-),(1,2,+)]           slices 0,1,4
// 17 paths, W_DIM=1184. cidx -> mv {16,8,8,4}, d3 {1,3,3,5}, outoff {0,16,40,64}
struct PathC { int key, woff, mu, cidx, d1, d2, d3, sla, slb; };
__constant__ PathC PC[17] = {
  {0, 0,    16, 0, 1,1,1, 0, 0},   // (0,0,0)
  {1, 256,  16, 1, 1,3,3, 0, 1},   // (0,1,1)
  {2, 384,  16, 3, 1,5,5, 0, 4},   // (0,2,3)
  {3, 448,  8,  1, 3,1,3, 16,0},   // (1,0,1)
  {4, 512,  8,  0, 3,3,1, 16,1},   // (1,1,0)
  {5, 640,  8,  2, 3,3,3, 16,1},   // (1,1,2)
  {6, 704,  8,  3, 3,3,5, 16,1},   // (1,1,3)
  {7, 736,  8,  1, 3,5,3, 16,4},   // (1,2,1)
  {3, 800,  8,  2, 3,1,3, 40,0},   // (2,0,2)
  {5, 864,  8,  1, 3,3,3, 40,1},   // (2,1,1)
  {7, 928,  8,  2, 3,5,3, 40,4},   // (2,2,2)
  {8, 992,  8,  3, 3,5,5, 40,4},   // (2,2,3)
  {9, 1024, 4,  3, 5,1,5, 64,0},   // (3,0,3)
  {10,1040, 4,  1, 5,3,3, 64,1},   // (3,1,1)
  {11,1072, 4,  0, 5,5,1, 64,4},   // (3,2,0)
  {12,1136, 4,  2, 5,5,3, 64,4},   // (3,2,2)
  {13,1168, 4,  3, 5,5,5, 64,4},   // (3,2,3)
};
__constant__ int MV4[4]   = {16, 8, 8, 4};
// fan per output irrep: 28, 44, 28, 40
__constant__ float FANS[4] = {0.18898223650461363f, 0.15075567228888181f,
                              0.18898223650461363f, 0.15811388300841897f};
// unique (l1,l2,l3) keys for wigner3j
__constant__ int KL[14][3] = {{0,0,0},{0,1,1},{0,2,2},{1,0,1},{1,1,0},{1,1,1},{1,1,2},
                              {1,2,1},{1,2,2},{2,0,2},{2,1,1},{2,2,0},{2,2,1},{2,2,2}};

// ---------------- on-device Wigner 3j (exact replica of reference) ----------------
__device__ double dfact(int n){ double r=1.0; for(int i=2;i<=n;++i) r*=(double)i; return r; }

__device__ double cg_coef(int j1,int m1,int j2,int m2,int j3,int m3){
  if (m1+m2 != m3) return 0.0;
  int kmin = max(0, max(j2-j3-m1, j1-j3+m2));
  int kmax = min(j1+j2-j3, min(j1-m1, j2+m2));
  if (kmax < kmin) return 0.0;
  double pref = sqrt((2.0*j3+1.0)*dfact(j3+j1-j2)*dfact(j3-j1+j2)*dfact(j1+j2-j3)/dfact(j1+j2+j3+1));
  pref *= sqrt(dfact(j3+m3)*dfact(j3-m3)*dfact(j1-m1)*dfact(j1+m1)*dfact(j2-m2)*dfact(j2+m2));
  double s = 0.0;
  for (int k=kmin;k<=kmax;++k){
    double d = dfact(k)*dfact(j1+j2-j3-k)*dfact(j1-m1-k)*dfact(j2+m2-k)*dfact(j3-j2+m1+k)*dfact(j3-j1-m2+k);
    s += ((k&1)? -1.0:1.0)/d;
  }
  return pref*s;
}

// builds Q into caller-provided (LDS) arrays
__device__ void buildQ(int l, double (*qr)[5], double (*qi)[5]){
  const double is2 = 0.70710678118654752440;
  for (int a=0;a<5;++a) for(int b=0;b<5;++b){ qr[a][b]=0.0; qi[a][b]=0.0; }
  for (int m=-l; m<0; ++m){
    qr[l+m][l-m] = is2;      // q[l+m, l+|m|] = 1/sqrt2
    qi[l+m][l+m] = -is2;     // q[l+m, l-|m|] = -i/sqrt2
  }
  qr[l][l] = 1.0;
  for (int m=1; m<=l; ++m){
    double sgn = (m & 1) ? -1.0 : 1.0;
    qr[l+m][l+m] = sgn*is2;
    qi[l+m][l-m] = sgn*is2;  // i*(-1)^m/sqrt2
  }
  if (l == 1) {              // multiply by (-i)^1: (r,i) -> (i,-r)
    for (int a=0;a<5;++a) for(int b=0;b<5;++b){ double r=qr[a][b], im=qi[a][b]; qr[a][b]=im; qi[a][b]=-r; }
  } else if (l == 2) {       // (-i)^2 = -1
    for (int a=0;a<5;++a) for(int b=0;b<5;++b){ qr[a][b]=-qr[a][b]; qi[a][b]=-qi[a][b]; }
  }
}

// one block per key; threads parallelize over output elements (i,j,k)
__global__ __launch_bounds__(128) void w3j_kernel(float* __restrict__ w3j) {
  int kid = blockIdx.x;
  int l1 = KL[kid][0], l2 = KL[kid][1], l3 = KL[kid][2];
  int d1 = 2*l1+1, d2 = 2*l2+1, d3 = 2*l3+1;
  int n = d1*d2*d3;
  int t = threadIdx.x;
  __shared__ double sqr[3][5][5], sqi[3][5][5];
  __shared__ double sC[25];
  __shared__ double red[128], red2[128];

  if (t < 3) {
    int l = (t==0)?l1:(t==1)?l2:l3;
    buildQ(l, sqr[t], sqi[t]);
  }
  if (t < d1*d2) {
    int a = t/d2, b = t - a*d2;
    int m1 = a-l1, m2 = b-l2, m3 = m1+m2;
    sC[a*5+b] = (m3 >= -l3 && m3 <= l3) ? cg_coef(l1,m1,l2,m2,l3,m3) : 0.0;
  }
  __syncthreads();

  double ar = 0.0, ai = 0.0;
  int i=0, j=0, k=0;
  if (t < n) {
    i = t/(d2*d3); int r = t - i*d2*d3; j = r/d3; k = r - j*d3;
    for (int a=0;a<d1;++a) for (int b=0;b<d2;++b) {
      double cv = sC[a*5+b];
      if (cv == 0.0) continue;
      int c = a + b - l1 - l2 + l3;          // l3 + m3
      if (c < 0 || c >= d3) continue;
      double q1r=sqr[0][a][i], q1i=sqi[0][a][i];
      double q2r=sqr[1][b][j], q2i=sqi[1][b][j];
      double q3r=sqr[2][c][k], q3i=sqi[2][c][k];
      double tr = q1r*q2r - q1i*q2i;
      double ti = q1r*q2i + q1i*q2r;
      double ur = tr*q3r + ti*q3i;           // * conj(q3)
      double ui = ti*q3r - tr*q3i;
      ar += ur*cv; ai += ui*cv;
    }
  }
  red[t]  = (t<n) ? fabs(ar) : 0.0;
  red2[t] = (t<n) ? fabs(ai) : 0.0;
  __syncthreads();
  for (int s=64; s>0; s>>=1) {
    if (t < s) { red[t] += red[t+s]; red2[t] += red2[t+s]; }
    __syncthreads();
  }
  bool use_re = red[0] > red2[0];
  double v = use_re ? ar : ai;
  __syncthreads();
  red[t] = (t<n) ? v*v : 0.0;
  __syncthreads();
  for (int s=64; s>0; s>>=1) {
    if (t < s) red[t] += red[t+s];
    __syncthreads();
  }
  double inv = 1.0/sqrt(red[0]);
  if (t < n) w3j[kid*125 + (i*d2+j)*d3 + k] = (float)(v*inv);
}

// ---------------- W2 transpose: W2T[col][h] = W2[h][col] ----------------
__global__ void w2t_kernel(const float* __restrict__ W2, float* __restrict__ W2T) {
  int idx = blockIdx.x*256 + threadIdx.x;
  if (idx < 64*WDIM) {
    int c = idx >> 6, h = idx & 63;
    W2T[idx] = W2[h*WDIM + c];
  }
}

// ---------------- fused radial-MLP + tensor-product + scatter ----------------
// block = 256 threads, 32 edges. thread = (e = t>>3, slot = t&7).
// Invariant: paths into c0 all have mv=16 (v = slot, slot+8); c1,c2 mv=8 (v=slot);
// c3 mv=4 (v=slot, slots>=4 idle) -> each thread statically owns 13 output floats.
__global__ __launch_bounds__(256, 2) void edge_kernel(
  const float* __restrict__ x, const int* __restrict__ eidx,
  const float* __restrict__ shg, const float* __restrict__ rbf,
  const float* __restrict__ W1, const float* __restrict__ b1,
  const float* __restrict__ W2T, const float* __restrict__ b2,
  const float* __restrict__ w3j, float* __restrict__ m_i, int E)
{
  __shared__ float s_act[BM][68];   // pad 68: conflict-free broadcast reads
  __shared__ float s_w2[64][68];    // staged W2T chunk [col][h]
  __shared__ float s_xj[BM][84];
  __shared__ float s_sh[BM][12];
  __shared__ float s_tmp[BM][81];   // pad 81: conflict-free
  int t = threadIdx.x;
  int e0 = blockIdx.x * BM;

  for (int idx = t; idx < BM*84; idx += 256) {
    int e = idx/84, d = idx - e*84;
    int ge = e0 + e;
    int j = (ge < E) ? eidx[E + ge] : 0;       // edge_index[1] = source
    s_xj[e][d] = x[j*84 + d];
  }
  for (int idx = t; idx < BM*9; idx += 256) {
    int e = idx/9, d = idx - e*9;
    int ge = min(e0 + e, E-1);
    s_sh[e][d] = shg[ge*9 + d];
  }
  for (int idx = t; idx < BM*64; idx += 256) {
    int e = idx >> 6, h = idx & 63;
    int ge = min(e0 + e, E-1);
    float s = b1[h];
    const float* r = rbf + ge*16;
    #pragma unroll
    for (int q = 0; q < 16; ++q) s = fmaf(r[q], W1[q*64 + h], s);
    s_act[e][h] = s / (1.f + expf(-s));        // silu
  }
  __syncthreads();

  int e = t >> 3, slot = t & 7;
  float a_reg[64];
  #pragma unroll
  for (int h4 = 0; h4 < 16; ++h4) {
    float4 v = *(const float4*)&s_act[e][h4*4];
    a_reg[h4*4+0]=v.x; a_reg[h4*4+1]=v.y; a_reg[h4*4+2]=v.z; a_reg[h4*4+3]=v.w;
  }
  float o0[2] = {0.f,0.f};
  float o1[3] = {0.f,0.f,0.f};
  float o2[3] = {0.f,0.f,0.f};
  float o3[5] = {0.f,0.f,0.f,0.f,0.f};

  for (int p = 0; p < 17; ++p) {
    PathC P = PC[p];
    int mv = MV4[P.cidx], d3 = P.d3;
    __syncthreads();   // prev path's readers done before tmp overwrite
    int md = P.mu * d3;
    for (int idx = t; idx < BM*md; idx += 256) {
      int ee = idx / md, r = idx - ee*md;
      int u = r / d3, kk = r - u*d3;
      const float* cg = w3j + P.key*125 + kk;
      float s = 0.f;
      for (int i = 0; i < P.d1; ++i) {
        float xa = s_xj[ee][P.sla + u*P.d1 + i];
        for (int jj = 0; jj < P.d2; ++jj)
          s = fmaf(xa * s_sh[ee][P.slb + jj], cg[(i*P.d2 + jj)*d3], s);
      }
      s_tmp[ee][r] = s;
    }
    int ncol_full = P.mu * mv;
    int CH = (ncol_full < 64) ? ncol_full : 64;
    int ucp = CH / mv;
    for (int u0 = 0; u0 < P.mu; u0 += ucp) {
      __syncthreads();  // prev chunk readers done; tmp writes visible after next sync
      for (int idx = t; idx < CH*64; idx += 256) {
        int c = idx >> 6, h = idx & 63;
        s_w2[c][h] = W2T[(P.woff + u0*mv + c)*64 + h];
      }
      __syncthreads();
      for (int uu = 0; uu < ucp; ++uu) {
        int u = u0 + uu;
        int vcount = (P.cidx == 0) ? 2 : 1;
        for (int vr = 0; vr < vcount; ++vr) {
          int v = slot + vr*8;
          if (v < mv) {
            int c = uu*mv + v;
            float wv = b2[P.woff + u*mv + v];
            #pragma unroll
            for (int h4 = 0; h4 < 16; ++h4) {
              float4 w4 = *(const float4*)&s_w2[c][h4*4];
              wv = fmaf(a_reg[h4*4+0], w4.x, wv);
              wv = fmaf(a_reg[h4*4+1], w4.y, wv);
              wv = fmaf(a_reg[h4*4+2], w4.z, wv);
              wv = fmaf(a_reg[h4*4+3], w4.w, wv);
            }
            const float* tp = &s_tmp[e][u*d3];
            if (P.cidx == 0) {
              o0[vr] = fmaf(tp[0], wv, o0[vr]);
            } else if (P.cidx == 1) {
              o1[0] = fmaf(tp[0], wv, o1[0]);
              o1[1] = fmaf(tp[1], wv, o1[1]);
              o1[2] = fmaf(tp[2], wv, o1[2]);
            } else if (P.cidx == 2) {
              o2[0] = fmaf(tp[0], wv, o2[0]);
              o2[1] = fmaf(tp[1], wv, o2[1]);
              o2[2] = fmaf(tp[2], wv, o2[2]);
            } else {
              #pragma unroll
              for (int kk = 0; kk < 5; ++kk) o3[kk] = fmaf(tp[kk], wv, o3[kk]);
            }
          }
        }
      }
    }
  }

  int ge = e0 + e;
  if (ge < E) {
    int ni = eidx[ge];                 // edge_index[0] = destination
    float* mrow = m_i + ni*84;
    atomicAdd(&mrow[slot],      o0[0]*FANS[0]);
    atomicAdd(&mrow[slot + 8],  o0[1]*FANS[0]);
    #pragma unroll
    for (int kk = 0; kk < 3; ++kk) atomicAdd(&mrow[16 + slot*3 + kk], o1[kk]*FANS[1]);
    #pragma unroll
    for (int kk = 0; kk < 3; ++kk) atomicAdd(&mrow[40 + slot*3 + kk], o2[kk]*FANS[2]);
    if (slot < 4) {
      #pragma unroll
      for (int kk = 0; kk < 5; ++kk) atomicAdd(&mrow[64 + slot*5 + kk], o3[kk]*FANS[3]);
    }
  }
}

// ---------------- block-diagonal o3_linear helpers ----------------
__device__ float o3lin_hh(const float* v, const float* w, int d) {
  float s = 0.f;
  if (d < 16) {
    #pragma unroll
    for (int u = 0; u < 16; ++u) s = fmaf(v[u], w[u*16 + d], s);
    return s * 0.25f;
  } else if (d < 40) {
    int loc = d-16, vv = loc/3, kk = loc - vv*3;
    #pragma unroll
    for (int u = 0; u < 8; ++u) s = fmaf(v[16 + u*3 + kk], w[256 + u*8 + vv], s);
    return s * 0.35355339059327373f;
  } else if (d < 64) {
    int loc = d-40, vv = loc/3, kk = loc - vv*3;
    #pragma unroll
    for (int u = 0; u < 8; ++u) s = fmaf(v[40 + u*3 + kk], w[320 + u*8 + vv], s);
    return s * 0.35355339059327373f;
  } else {
    int loc = d-64, vv = loc/5, kk = loc - vv*5;
    #pragma unroll
    for (int u = 0; u < 4; ++u) s = fmaf(v[64 + u*5 + kk], w[384 + u*4 + vv], s);
    return s * 0.5f;
  }
}

__device__ float o3lin_pre(const float* v, const float* w, int d) {
  float s = 0.f;
  if (d < 16) {
    #pragma unroll
    for (int u = 0; u < 16; ++u) s = fmaf(v[u], w[u*16 + d], s);
    return s * 0.25f;
  } else if (d < 36) {
    int vv = d - 16;
    #pragma unroll
    for (int u = 0; u < 16; ++u) s = fmaf(v[u], w[256 + u*20 + vv], s);
    return s * 0.25f;
  } else if (d < 60) {
    int loc = d-36, vv = loc/3, kk = loc - vv*3;
    #pragma unroll
    for (int u = 0; u < 8; ++u) s = fmaf(v[16 + u*3 + kk], w[576 + u*8 + vv], s);
    return s * 0.35355339059327373f;
  } else if (d < 84) {
    int loc = d-60, vv = loc/3, kk = loc - vv*3;
    #pragma unroll
    for (int u = 0; u < 8; ++u) s = fmaf(v[40 + u*3 + kk], w[640 + u*8 + vv], s);
    return s * 0.35355339059327373f;
  } else {
    int loc = d-84, vv = loc/5, kk = loc - vv*5;
    #pragma unroll
    for (int u = 0; u < 4; ++u) s = fmaf(v[64 + u*5 + kk], w[704 + u*4 + vv], s);
    return s * 0.5f;
  }
}

// ---------------- h1 = x + lin_res(m_i); accumulate bn stats ----------------
__global__ __launch_bounds__(256) void node_res_kernel(
  const float* __restrict__ x, const float* __restrict__ m_i,
  const float* __restrict__ lw, float* __restrict__ h1,
  float* __restrict__ stats, int N)
{
  __shared__ float s_m[4][84];
  __shared__ float s_sum[16];
  __shared__ float s_sq[36];
  int t = threadIdx.x;
  int n0 = blockIdx.x*4;
  if (t < 16) s_sum[t] = 0.f;
  if (t < 36) s_sq[t] = 0.f;
  for (int idx = t; idx < 4*84; idx += 256) {
    int e = idx/84, d = idx - e*84;
    int n = n0 + e;
    s_m[e][d] = (n < N) ? m_i[n*84 + d] : 0.f;
  }
  __syncthreads();
  int w = t >> 6, lane = t & 63;
  int n = n0 + w;
  for (int rep = 0; rep < 2; ++rep) {
    int d = lane + rep*64;
    if (d < 84 && n < N) {
      float v = x[n*84 + d] + o3lin_hh(s_m[w], lw, d);
      h1[n*84 + d] = v;
      if (d < 16) {
        atomicAdd(&s_sum[d], v);
        atomicAdd(&s_sq[d], v*v);
      } else {
        int ch = (d < 40) ? 16 + (d-16)/3 : (d < 64) ? 24 + (d-40)/3 : 32 + (d-64)/5;
        atomicAdd(&s_sq[ch], v*v);
      }
    }
  }
  __syncthreads();
  if (t < 16) atomicAdd(&stats[t], s_sum[t]);
  if (t < 36) atomicAdd(&stats[16 + t], s_sq[t]);
}

// ---------------- batchnorm finalize: scale/shift per channel ----------------
__global__ void bn_finalize_kernel(const float* __restrict__ stats,
                                   const float* __restrict__ bnw,
                                   const float* __restrict__ bnb,
                                   float* __restrict__ scsh, int N)
{
  int t = threadIdx.x;
  if (t >= 36) return;
  float q = stats[16 + t];
  float scale, shift = 0.f;
  if (t < 16) {
    float mean = stats[t] / (float)N;
    float var  = q / (float)N - mean*mean;        // E[(f-mean)^2]
    scale = bnw[t] / sqrtf(var + 1e-5f);
    shift = bnb[t] - mean*scale;
  } else {
    float dd = (t < 32) ? 3.f : 5.f;
    float var = q / ((float)N * dd);
    scale = bnw[t] / sqrtf(var + 1e-5f);
  }
  scsh[t] = scale;
  scsh[36 + t] = shift;
}

// ---------------- bn apply + pre_gate + gate + post_gate ----------------
__global__ __launch_bounds__(256) void node_out_kernel(
  const float* __restrict__ h1, const float* __restrict__ scsh,
  const float* __restrict__ wpre, const float* __restrict__ wpost,
  float* __restrict__ out, int N)
{
  __shared__ float s_y[4][84];
  __shared__ float s_p[4][104];
  __shared__ float s_g[4][84];
  int t = threadIdx.x;
  int n0 = blockIdx.x*4;
  for (int idx = t; idx < 4*84; idx += 256) {
    int e = idx/84, d = idx - e*84;
    int n = n0 + e;
    float v = (n < N) ? h1[n*84 + d] : 0.f;
    int ch = (d < 16) ? d : (d < 40) ? 16 + (d-16)/3 : (d < 64) ? 24 + (d-40)/3 : 32 + (d-64)/5;
    s_y[e][d] = v*scsh[ch] + scsh[36 + ch];
  }
  __syncthreads();
  int w = t >> 6, lane = t & 63;
  for (int rep = 0; rep < 2; ++rep) {
    int d = lane + rep*64;
    if (d < 104) s_p[w][d] = o3lin_pre(s_y[w], wpre, d);
  }
  __syncthreads();
  for (int rep = 0; rep < 2; ++rep) {
    int d = lane + rep*64;
    if (d < 84) {
      float v;
      if (d < 16)      { float sv = s_p[w][d]; v = sv / (1.f + expf(-sv)); }
      else if (d < 40) { int loc = d-16; v = s_p[w][36 + loc] / (1.f + expf(-s_p[w][16 + loc/3])); }
      else if (d < 64) { int loc = d-40; v = s_p[w][60 + loc] / (1.f + expf(-s_p[w][24 + loc/3])); }
      else             { int loc = d-64; v = s_p[w][84 + loc] / (1.f + expf(-s_p[w][32 + loc/5])); }
      s_g[w][d] = v;
    }
  }
  __syncthreads();
  int n = n0 + w;
  for (int rep = 0; rep < 2; ++rep) {
    int d = lane + rep*64;
    if (d < 84 && n < N) out[n*84 + d] = o3lin_hh(s_g[w], wpost, d);
  }
}

// ---------------- launch ----------------
extern "C" void kernel_launch(void* const* d_in, const int* in_sizes, int n_in,
                              void* d_out, int out_size, void* d_ws, size_t ws_size,
                              hipStream_t stream)
{
  const float* x    = (const float*)d_in[0];
  const int*   eidx = (const int*)d_in[1];
  const float* shg  = (const float*)d_in[2];
  const float* rbf  = (const float*)d_in[3];
  const float* W1   = (const float*)d_in[4];
  const float* b1   = (const float*)d_in[5];
  const float* W2   = (const float*)d_in[6];
  const float* b2   = (const float*)d_in[7];
  const float* lrw  = (const float*)d_in[8];
  const float* prw  = (const float*)d_in[9];
  const float* pgw  = (const float*)d_in[10];
  const float* bnw  = (const float*)d_in[11];
  const float* bnb  = (const float*)d_in[12];
  int N = in_sizes[0] / 84;
  int E = in_sizes[1] / 2;

  // ws layout (floats): m_i[N*84] | stats[64] | scsh[80] | h1[N*84] | w3j[1750] | W2T[75776]
  float* ws    = (float*)d_ws;
  float* m_i   = ws;
  float* stats = ws + (size_t)N*84;
  float* scsh  = stats + 64;
  float* h1    = scsh + 80;
  float* w3j   = h1 + (size_t)N*84;
  float* W2T   = w3j + 14*125;
  // total ~1.76M floats (~7 MB)

  hipMemsetAsync(m_i, 0, ((size_t)N*84 + 64)*sizeof(float), stream);
  w3j_kernel<<<14, 128, 0, stream>>>(w3j);
  w2t_kernel<<<(64*WDIM + 255)/256, 256, 0, stream>>>(W2, W2T);
  edge_kernel<<<(E + BM - 1)/BM, 256, 0, stream>>>(x, eidx, shg, rbf, W1, b1, W2T, b2, w3j, m_i, E);
  node_res_kernel<<<(N + 3)/4, 256, 0, stream>>>(x, m_i, lrw, h1, stats, N);
  bn_finalize_kernel<<<1, 64, 0, stream>>>(stats, bnw, bnb, scsh, N);
  node_out_kernel<<<(N + 3)/4, 256, 0, stream>>>(h1, scsh, prw, pgw, (float*)d_out, N);
}

// Round 8
// 878.762 us; speedup vs baseline: 4.9382x; 1.5457x over previous
//
#include <hip/hip_runtime.h>
#include <math.h>

#define DIMH 84
#define WDIM 1184

typedef __attribute__((ext_vector_type(8))) short bf16x8;
typedef __attribute__((ext_vector_type(4))) float f32x4;

// ---------------- path / irrep constant tables ----------------
// IRR_H = [(16,0,+),(8,1,-),(8,1,+),(4,2,+)]  slices 0,16,40,64
// IRR_E = [(1,0,+),(1,1,-),(1,2,+)]           slices 0,1,4
struct PathC { int key, woff, mu, cidx, d1, d2, d3, sla, slb; };
__constant__ PathC PC[17] = {
  {0, 0,    16, 0, 1,1,1, 0, 0},   // (0,0,0)
  {1, 256,  16, 1, 1,3,3, 0, 1},   // (0,1,1)
  {2, 384,  16, 3, 1,5,5, 0, 4},   // (0,2,3)
  {3, 448,  8,  1, 3,1,3, 16,0},   // (1,0,1)
  {4, 512,  8,  0, 3,3,1, 16,1},   // (1,1,0)
  {5, 640,  8,  2, 3,3,3, 16,1},   // (1,1,2)
  {6, 704,  8,  3, 3,3,5, 16,1},   // (1,1,3)
  {7, 736,  8,  1, 3,5,3, 16,4},   // (1,2,1)
  {3, 800,  8,  2, 3,1,3, 40,0},   // (2,0,2)
  {5, 864,  8,  1, 3,3,3, 40,1},   // (2,1,1)
  {7, 928,  8,  2, 3,5,3, 40,4},   // (2,2,2)
  {8, 992,  8,  3, 3,5,5, 40,4},   // (2,2,3)
  {9, 1024, 4,  3, 5,1,5, 64,0},   // (3,0,3)
  {10,1040, 4,  1, 5,3,3, 64,1},   // (3,1,1)
  {11,1072, 4,  0, 5,5,1, 64,4},   // (3,2,0)
  {12,1136, 4,  2, 5,5,3, 64,4},   // (3,2,2)
  {13,1168, 4,  3, 5,5,5, 64,4},   // (3,2,3)
};
// unique (l1,l2,l3) keys for wigner3j
__constant__ int KL[14][3] = {{0,0,0},{0,1,1},{0,2,2},{1,0,1},{1,1,0},{1,1,1},{1,1,2},
                              {1,2,1},{1,2,2},{2,0,2},{2,1,1},{2,2,0},{2,2,1},{2,2,2}};

__device__ __forceinline__ short f2bf(float f) {   // f32 -> bf16 (RNE)
  unsigned u = __float_as_uint(f);
  unsigned r = u + 0x7FFFu + ((u >> 16) & 1u);
  return (short)(r >> 16);
}

// ---------------- on-device Wigner 3j (exact replica of reference) ----------------
__device__ double dfact(int n){ double r=1.0; for(int i=2;i<=n;++i) r*=(double)i; return r; }

__device__ double cg_coef(int j1,int m1,int j2,int m2,int j3,int m3){
  if (m1+m2 != m3) return 0.0;
  int kmin = max(0, max(j2-j3-m1, j1-j3+m2));
  int kmax = min(j1+j2-j3, min(j1-m1, j2+m2));
  if (kmax < kmin) return 0.0;
  double pref = sqrt((2.0*j3+1.0)*dfact(j3+j1-j2)*dfact(j3-j1+j2)*dfact(j1+j2-j3)/dfact(j1+j2+j3+1));
  pref *= sqrt(dfact(j3+m3)*dfact(j3-m3)*dfact(j1-m1)*dfact(j1+m1)*dfact(j2-m2)*dfact(j2+m2));
  double s = 0.0;
  for (int k=kmin;k<=kmax;++k){
    double d = dfact(k)*dfact(j1+j2-j3-k)*dfact(j1-m1-k)*dfact(j2+m2-k)*dfact(j3-j2+m1+k)*dfact(j3-j1-m2+k);
    s += ((k&1)? -1.0:1.0)/d;
  }
  return pref*s;
}

__device__ void buildQ(int l, double (*qr)[5], double (*qi)[5]){
  const double is2 = 0.70710678118654752440;
  for (int a=0;a<5;++a) for(int b=0;b<5;++b){ qr[a][b]=0.0; qi[a][b]=0.0; }
  for (int m=-l; m<0; ++m){
    qr[l+m][l-m] = is2;
    qi[l+m][l+m] = -is2;
  }
  qr[l][l] = 1.0;
  for (int m=1; m<=l; ++m){
    double sgn = (m & 1) ? -1.0 : 1.0;
    qr[l+m][l+m] = sgn*is2;
    qi[l+m][l-m] = sgn*is2;
  }
  if (l == 1) {
    for (int a=0;a<5;++a) for(int b=0;b<5;++b){ double r=qr[a][b], im=qi[a][b]; qr[a][b]=im; qi[a][b]=-r; }
  } else if (l == 2) {
    for (int a=0;a<5;++a) for(int b=0;b<5;++b){ qr[a][b]=-qr[a][b]; qi[a][b]=-qi[a][b]; }
  }
}

__global__ __launch_bounds__(128) void w3j_kernel(float* __restrict__ w3j) {
  int kid = blockIdx.x;
  int l1 = KL[kid][0], l2 = KL[kid][1], l3 = KL[kid][2];
  int d1 = 2*l1+1, d2 = 2*l2+1, d3 = 2*l3+1;
  int n = d1*d2*d3;
  int t = threadIdx.x;
  __shared__ double sqr[3][5][5], sqi[3][5][5];
  __shared__ double sC[25];
  __shared__ double red[128], red2[128];

  if (t < 3) {
    int l = (t==0)?l1:(t==1)?l2:l3;
    buildQ(l, sqr[t], sqi[t]);
  }
  if (t < d1*d2) {
    int a = t/d2, b = t - a*d2;
    int m1 = a-l1, m2 = b-l2, m3 = m1+m2;
    sC[a*5+b] = (m3 >= -l3 && m3 <= l3) ? cg_coef(l1,m1,l2,m2,l3,m3) : 0.0;
  }
  __syncthreads();

  double ar = 0.0, ai = 0.0;
  int i=0, j=0, k=0;
  if (t < n) {
    i = t/(d2*d3); int r = t - i*d2*d3; j = r/d3; k = r - j*d3;
    for (int a=0;a<d1;++a) for (int b=0;b<d2;++b) {
      double cv = sC[a*5+b];
      if (cv == 0.0) continue;
      int c = a + b - l1 - l2 + l3;
      if (c < 0 || c >= d3) continue;
      double q1r=sqr[0][a][i], q1i=sqi[0][a][i];
      double q2r=sqr[1][b][j], q2i=sqi[1][b][j];
      double q3r=sqr[2][c][k], q3i=sqi[2][c][k];
      double tr = q1r*q2r - q1i*q2i;
      double ti = q1r*q2i + q1i*q2r;
      double ur = tr*q3r + ti*q3i;
      double ui = ti*q3r - tr*q3i;
      ar += ur*cv; ai += ui*cv;
    }
  }
  red[t]  = (t<n) ? fabs(ar) : 0.0;
  red2[t] = (t<n) ? fabs(ai) : 0.0;
  __syncthreads();
  for (int s=64; s>0; s>>=1) {
    if (t < s) { red[t] += red[t+s]; red2[t] += red2[t+s]; }
    __syncthreads();
  }
  bool use_re = red[0] > red2[0];
  double v = use_re ? ar : ai;
  __syncthreads();
  red[t] = (t<n) ? v*v : 0.0;
  __syncthreads();
  for (int s=64; s>0; s>>=1) {
    if (t < s) red[t] += red[t+s];
    __syncthreads();
  }
  double inv = 1.0/sqrt(red[0]);
  if (t < n) w3j[kid*125 + (i*d2+j)*d3 + k] = (float)(v*inv);
}

// ---------------- W2 transpose -> bf16: W2Tb[col][h] = bf16(W2[h][col]) ----------------
__global__ void w2t_kernel(const float* __restrict__ W2, short* __restrict__ W2Tb) {
  int idx = blockIdx.x*256 + threadIdx.x;
  if (idx < 64*WDIM) {
    int c = idx >> 6, h = idx & 63;
    W2Tb[idx] = f2bf(W2[h*WDIM + c]);
  }
}

// ---------------- tp compute (cooperative, generic over path) ----------------
__device__ __forceinline__ void tp_compute(int p, int t, const float* __restrict__ w3j,
    float (*s_xj)[84], float (*s_sh)[12], float (*s_tp)[84])
{
  PathC P = PC[p];
  int md = P.mu * P.d3;
  for (int idx = t; idx < 64*md; idx += 256) {
    int ee = idx / md, r = idx - ee*md;
    int u = r / P.d3, kk = r - u*P.d3;
    const float* cg = w3j + P.key*125 + kk;
    float s = 0.f;
    for (int i = 0; i < P.d1; ++i) {
      float xa = s_xj[ee][P.sla + u*P.d1 + i];
      for (int jj = 0; jj < P.d2; ++jj)
        s = fmaf(xa * s_sh[ee][P.slb + jj], cg[(i*P.d2 + jj)*P.d3], s);
    }
    s_tp[ee][r] = s;
  }
}

// ---------------- fused radial-MLP(MFMA) + tensor-product + scatter ----------------
// block = 256 threads = 4 waves, 64 edges; wave w owns edges w*16..w*16+15 (M=16).
// GEMM: w[64 edges][1184 cols] = act(64x64) @ W2Tb^T, bf16 MFMA 16x16x32, b2 in C-init.
// A-frag: lane holds act[wv*16 + (ln&15)][8*(ln>>4)+j]  (loop-invariant!)
// B-frag: lane holds W2Tb[cb + (ln&15)][8*(ln>>4)+j]    (B^T-row layout, m92-verified)
// C-frag: row(edge) = (ln>>4)*4+reg, col = ln&15        (m89-verified)
__global__ __launch_bounds__(256, 2) void edge_kernel(
  const float* __restrict__ x, const int* __restrict__ eidx,
  const float* __restrict__ shg, const float* __restrict__ rbf,
  const float* __restrict__ W1, const float* __restrict__ b1,
  const short* __restrict__ W2Tb, const float* __restrict__ b2,
  const float* __restrict__ w3j, float* __restrict__ m_i, int E)
{
  __shared__ __align__(16) short s_act[64][72];   // bf16 bits, pad 72 (bank-stagger)
  __shared__ float s_xj[64][84];
  __shared__ float s_sh[64][12];
  __shared__ float s_tp[64][84];
  int t = threadIdx.x;
  int e0 = blockIdx.x * 64;

  for (int idx = t; idx < 64*84; idx += 256) {
    int e = idx/84, d = idx - e*84;
    int ge = e0 + e;
    int j = (ge < E) ? eidx[E + ge] : 0;
    s_xj[e][d] = x[j*84 + d];
  }
  for (int idx = t; idx < 64*9; idx += 256) {
    int e = idx/9, d = idx - e*9;
    int ge = min(e0 + e, E-1);
    s_sh[e][d] = shg[ge*9 + d];
  }
  for (int idx = t; idx < 64*64; idx += 256) {
    int e = idx >> 6, h = idx & 63;
    int ge = min(e0 + e, E-1);
    float s = b1[h];
    const float* r = rbf + ge*16;
    #pragma unroll
    for (int q = 0; q < 16; ++q) s = fmaf(r[q], W1[q*64 + h], s);
    s = s / (1.f + expf(-s));                   // silu
    s_act[e][h] = f2bf(s);
  }
  __syncthreads();

  int wv = t >> 6, ln = t & 63;
  int col16 = ln & 15, kg = ln >> 4;
  int wrow = wv*16 + kg*4;                       // first of this lane's 4 C-row edges

  // loop-invariant A fragments (this wave's 16 edges, K=64 in two 32-chunks)
  bf16x8 a0 = *(const bf16x8*)&s_act[wv*16 + col16][kg*8];
  bf16x8 a1 = *(const bf16x8*)&s_act[wv*16 + col16][32 + kg*8];

  float acc0[4][1] = {};
  float acc1[4][3] = {};
  float acc2[4][3] = {};
  float acc3[4][5] = {};

#define PROC(WOFF, NTILES, D3, UPT, LOGMV, ACC)                                   \
  {                                                                                \
    _Pragma("unroll")                                                              \
    for (int nt = 0; nt < NTILES; ++nt) {                                          \
      int cb = WOFF + nt*16;                                                       \
      bf16x8 bb0 = *(const bf16x8*)&W2Tb[(cb + col16)*64 + kg*8];                  \
      bf16x8 bb1 = *(const bf16x8*)&W2Tb[(cb + col16)*64 + 32 + kg*8];             \
      float b2v = b2[cb + col16];                                                  \
      f32x4 c = {b2v, b2v, b2v, b2v};                                              \
      c = __builtin_amdgcn_mfma_f32_16x16x32_bf16(a0, bb0, c, 0, 0, 0);            \
      c = __builtin_amdgcn_mfma_f32_16x16x32_bf16(a1, bb1, c, 0, 0, 0);            \
      int u = nt*UPT + (col16 >> LOGMV);                                           \
      _Pragma("unroll")                                                            \
      for (int r = 0; r < 4; ++r) {                                                \
        const float* tpp = &s_tp[wrow + r][u*D3];                                  \
        float cf = c[r];                                                           \
        _Pragma("unroll")                                                          \
        for (int k = 0; k < D3; ++k) ACC[r][k] = fmaf(tpp[k], cf, ACC[r][k]);      \
      }                                                                            \
    }                                                                              \
  }

#define PATH(P_, PROCCALL)                                                         \
  __syncthreads();                                                                 \
  tp_compute(P_, t, w3j, s_xj, s_sh, s_tp);                                        \
  __syncthreads();                                                                 \
  PROCCALL

  PATH(0,  PROC(0,    16, 1, 1, 4, acc0))
  PATH(1,  PROC(256,   8, 3, 2, 3, acc1))
  PATH(2,  PROC(384,   4, 5, 4, 2, acc3))
  PATH(3,  PROC(448,   4, 3, 2, 3, acc1))
  PATH(4,  PROC(512,   8, 1, 1, 4, acc0))
  PATH(5,  PROC(640,   4, 3, 2, 3, acc2))
  PATH(6,  PROC(704,   2, 5, 4, 2, acc3))
  PATH(7,  PROC(736,   4, 3, 2, 3, acc1))
  PATH(8,  PROC(800,   4, 3, 2, 3, acc2))
  PATH(9,  PROC(864,   4, 3, 2, 3, acc1))
  PATH(10, PROC(928,   4, 3, 2, 3, acc2))
  PATH(11, PROC(992,   2, 5, 4, 2, acc3))
  PATH(12, PROC(1024,  1, 5, 4, 2, acc3))
  PATH(13, PROC(1040,  2, 3, 2, 3, acc1))
  PATH(14, PROC(1072,  4, 1, 1, 4, acc0))
  PATH(15, PROC(1136,  2, 3, 2, 3, acc2))
  PATH(16, PROC(1168,  1, 5, 4, 2, acc3))

  // combine u-subgroups across lanes sharing the same v (linear, deferred to end):
  // mv=8 -> lanes c and c^8; mv=4 -> c, c^4, c^8, c^12
  #pragma unroll
  for (int r = 0; r < 4; ++r) {
    #pragma unroll
    for (int k = 0; k < 3; ++k) {
      acc1[r][k] += __shfl_xor(acc1[r][k], 8);
      acc2[r][k] += __shfl_xor(acc2[r][k], 8);
    }
    #pragma unroll
    for (int k = 0; k < 5; ++k) {
      float v = acc3[r][k];
      v += __shfl_xor(v, 8);
      v += __shfl_xor(v, 4);
      acc3[r][k] = v;
    }
  }

  const float FAN0 = 0.18898223650461363f;   // 1/sqrt(28)
  const float FAN1 = 0.15075567228888181f;   // 1/sqrt(44)
  const float FAN2 = 0.18898223650461363f;   // 1/sqrt(28)
  const float FAN3 = 0.15811388300841897f;   // 1/sqrt(40)
  #pragma unroll
  for (int r = 0; r < 4; ++r) {
    int ge = e0 + wrow + r;
    if (ge >= E) continue;
    int ni = eidx[ge];                         // edge_index[0] = destination
    float* mrow = m_i + ni*84;
    atomicAdd(&mrow[col16], acc0[r][0]*FAN0);
    if (col16 < 8) {
      #pragma unroll
      for (int k = 0; k < 3; ++k) atomicAdd(&mrow[16 + col16*3 + k], acc1[r][k]*FAN1);
      #pragma unroll
      for (int k = 0; k < 3; ++k) atomicAdd(&mrow[40 + col16*3 + k], acc2[r][k]*FAN2);
    }
    if (col16 < 4) {
      #pragma unroll
      for (int k = 0; k < 5; ++k) atomicAdd(&mrow[64 + col16*5 + k], acc3[r][k]*FAN3);
    }
  }
#undef PROC
#undef PATH
}

// ---------------- block-diagonal o3_linear helpers ----------------
__device__ float o3lin_hh(const float* v, const float* w, int d) {
  float s = 0.f;
  if (d < 16) {
    #pragma unroll
    for (int u = 0; u < 16; ++u) s = fmaf(v[u], w[u*16 + d], s);
    return s * 0.25f;
  } else if (d < 40) {
    int loc = d-16, vv = loc/3, kk = loc - vv*3;
    #pragma unroll
    for (int u = 0; u < 8; ++u) s = fmaf(v[16 + u*3 + kk], w[256 + u*8 + vv], s);
    return s * 0.35355339059327373f;
  } else if (d < 64) {
    int loc = d-40, vv = loc/3, kk = loc - vv*3;
    #pragma unroll
    for (int u = 0; u < 8; ++u) s = fmaf(v[40 + u*3 + kk], w[320 + u*8 + vv], s);
    return s * 0.35355339059327373f;
  } else {
    int loc = d-64, vv = loc/5, kk = loc - vv*5;
    #pragma unroll
    for (int u = 0; u < 4; ++u) s = fmaf(v[64 + u*5 + kk], w[384 + u*4 + vv], s);
    return s * 0.5f;
  }
}

__device__ float o3lin_pre(const float* v, const float* w, int d) {
  float s = 0.f;
  if (d < 16) {
    #pragma unroll
    for (int u = 0; u < 16; ++u) s = fmaf(v[u], w[u*16 + d], s);
    return s * 0.25f;
  } else if (d < 36) {
    int vv = d - 16;
    #pragma unroll
    for (int u = 0; u < 16; ++u) s = fmaf(v[u], w[256 + u*20 + vv], s);
    return s * 0.25f;
  } else if (d < 60) {
    int loc = d-36, vv = loc/3, kk = loc - vv*3;
    #pragma unroll
    for (int u = 0; u < 8; ++u) s = fmaf(v[16 + u*3 + kk], w[576 + u*8 + vv], s);
    return s * 0.35355339059327373f;
  } else if (d < 84) {
    int loc = d-60, vv = loc/3, kk = loc - vv*3;
    #pragma unroll
    for (int u = 0; u < 8; ++u) s = fmaf(v[40 + u*3 + kk], w[640 + u*8 + vv], s);
    return s * 0.35355339059327373f;
  } else {
    int loc = d-84, vv = loc/5, kk = loc - vv*5;
    #pragma unroll
    for (int u = 0; u < 4; ++u) s = fmaf(v[64 + u*5 + kk], w[704 + u*4 + vv], s);
    return s * 0.5f;
  }
}

// ---------------- h1 = x + lin_res(m_i); accumulate bn stats ----------------
__global__ __launch_bounds__(256) void node_res_kernel(
  const float* __restrict__ x, const float* __restrict__ m_i,
  const float* __restrict__ lw, float* __restrict__ h1,
  float* __restrict__ stats, int N)
{
  __shared__ float s_m[4][84];
  __shared__ float s_sum[16];
  __shared__ float s_sq[36];
  int t = threadIdx.x;
  int n0 = blockIdx.x*4;
  if (t < 16) s_sum[t] = 0.f;
  if (t < 36) s_sq[t] = 0.f;
  for (int idx = t; idx < 4*84; idx += 256) {
    int e = idx/84, d = idx - e*84;
    int n = n0 + e;
    s_m[e][d] = (n < N) ? m_i[n*84 + d] : 0.f;
  }
  __syncthreads();
  int w = t >> 6, lane = t & 63;
  int n = n0 + w;
  for (int rep = 0; rep < 2; ++rep) {
    int d = lane + rep*64;
    if (d < 84 && n < N) {
      float v = x[n*84 + d] + o3lin_hh(s_m[w], lw, d);
      h1[n*84 + d] = v;
      if (d < 16) {
        atomicAdd(&s_sum[d], v);
        atomicAdd(&s_sq[d], v*v);
      } else {
        int ch = (d < 40) ? 16 + (d-16)/3 : (d < 64) ? 24 + (d-40)/3 : 32 + (d-64)/5;
        atomicAdd(&s_sq[ch], v*v);
      }
    }
  }
  __syncthreads();
  if (t < 16) atomicAdd(&stats[t], s_sum[t]);
  if (t < 36) atomicAdd(&stats[16 + t], s_sq[t]);
}

// ---------------- batchnorm finalize ----------------
__global__ void bn_finalize_kernel(const float* __restrict__ stats,
                                   const float* __restrict__ bnw,
                                   const float* __restrict__ bnb,
                                   float* __restrict__ scsh, int N)
{
  int t = threadIdx.x;
  if (t >= 36) return;
  float q = stats[16 + t];
  float scale, shift = 0.f;
  if (t < 16) {
    float mean = stats[t] / (float)N;
    float var  = q / (float)N - mean*mean;
    scale = bnw[t] / sqrtf(var + 1e-5f);
    shift = bnb[t] - mean*scale;
  } else {
    float dd = (t < 32) ? 3.f : 5.f;
    float var = q / ((float)N * dd);
    scale = bnw[t] / sqrtf(var + 1e-5f);
  }
  scsh[t] = scale;
  scsh[36 + t] = shift;
}

// ---------------- bn apply + pre_gate + gate + post_gate ----------------
__global__ __launch_bounds__(256) void node_out_kernel(
  const float* __restrict__ h1, const float* __restrict__ scsh,
  const float* __restrict__ wpre, const float* __restrict__ wpost,
  float* __restrict__ out, int N)
{
  __shared__ float s_y[4][84];
  __shared__ float s_p[4][104];
  __shared__ float s_g[4][84];
  int t = threadIdx.x;
  int n0 = blockIdx.x*4;
  for (int idx = t; idx < 4*84; idx += 256) {
    int e = idx/84, d = idx - e*84;
    int n = n0 + e;
    float v = (n < N) ? h1[n*84 + d] : 0.f;
    int ch = (d < 16) ? d : (d < 40) ? 16 + (d-16)/3 : (d < 64) ? 24 + (d-40)/3 : 32 + (d-64)/5;
    s_y[e][d] = v*scsh[ch] + scsh[36 + ch];
  }
  __syncthreads();
  int w = t >> 6, lane = t & 63;
  for (int rep = 0; rep < 2; ++rep) {
    int d = lane + rep*64;
    if (d < 104) s_p[w][d] = o3lin_pre(s_y[w], wpre, d);
  }
  __syncthreads();
  for (int rep = 0; rep < 2; ++rep) {
    int d = lane + rep*64;
    if (d < 84) {
      float v;
      if (d < 16)      { float sv = s_p[w][d]; v = sv / (1.f + expf(-sv)); }
      else if (d < 40) { int loc = d-16; v = s_p[w][36 + loc] / (1.f + expf(-s_p[w][16 + loc/3])); }
      else if (d < 64) { int loc = d-40; v = s_p[w][60 + loc] / (1.f + expf(-s_p[w][24 + loc/3])); }
      else             { int loc = d-64; v = s_p[w][84 + loc] / (1.f + expf(-s_p[w][32 + loc/5])); }
      s_g[w][d] = v;
    }
  }
  __syncthreads();
  int n = n0 + w;
  for (int rep = 0; rep < 2; ++rep) {
    int d = lane + rep*64;
    if (d < 84 && n < N) out[n*84 + d] = o3lin_hh(s_g[w], wpost, d);
  }
}

// ---------------- launch ----------------
extern "C" void kernel_launch(void* const* d_in, const int* in_sizes, int n_in,
                              void* d_out, int out_size, void* d_ws, size_t ws_size,
                              hipStream_t stream)
{
  const float* x    = (const float*)d_in[0];
  const int*   eidx = (const int*)d_in[1];
  const float* shg  = (const float*)d_in[2];
  const float* rbf  = (const float*)d_in[3];
  const float* W1   = (const float*)d_in[4];
  const float* b1   = (const float*)d_in[5];
  const float* W2   = (const float*)d_in[6];
  const float* b2   = (const float*)d_in[7];
  const float* lrw  = (const float*)d_in[8];
  const float* prw  = (const float*)d_in[9];
  const float* pgw  = (const float*)d_in[10];
  const float* bnw  = (const float*)d_in[11];
  const float* bnb  = (const float*)d_in[12];
  int N = in_sizes[0] / 84;
  int E = in_sizes[1] / 2;

  // ws layout (floats): m_i[N*84] | stats[64] | scsh[80] | h1[N*84] | w3j[1750] | W2Tb(bf16)
  float* ws    = (float*)d_ws;
  float* m_i   = ws;
  float* stats = ws + (size_t)N*84;
  float* scsh  = stats + 64;
  float* h1    = scsh + 80;
  float* w3j   = h1 + (size_t)N*84;
  short* W2Tb  = (short*)(w3j + 14*125);

  hipMemsetAsync(m_i, 0, ((size_t)N*84 + 64)*sizeof(float), stream);
  w3j_kernel<<<14, 128, 0, stream>>>(w3j);
  w2t_kernel<<<(64*WDIM + 255)/256, 256, 0, stream>>>(W2, W2Tb);
  edge_kernel<<<(E + 63)/64, 256, 0, stream>>>(x, eidx, shg, rbf, W1, b1, W2Tb, b2, w3j, m_i, E);
  node_res_kernel<<<(N + 3)/4, 256, 0, stream>>>(x, m_i, lrw, h1, stats, N);
  bn_finalize_kernel<<<1, 64, 0, stream>>>(stats, bnw, bnb, scsh, N);
  node_out_kernel<<<(N + 3)/4, 256, 0, stream>>>(h1, scsh, prw, pgw, (float*)d_out, N);
}

// Round 10
// 569.951 us; speedup vs baseline: 7.6138x; 1.5418x over previous
//
#include <hip/hip_runtime.h>
#include <math.h>

#define DIMH 84
#define WDIM 1184

typedef __attribute__((ext_vector_type(8))) short bf16x8;
typedef __attribute__((ext_vector_type(4))) float f32x4;

// ---------------- path / irrep constant tables ----------------
// IRR_H = [(16,0,+),(8,1,-),(8,1,+),(4,2,+)]  slices 0,16,40,64
// IRR_E = [(1,0,+),(1,1,-),(1,2,+)]           slices 0,1,4
// unique (l1,l2,l3) keys for wigner3j
__constant__ int KL[14][3] = {{0,0,0},{0,1,1},{0,2,2},{1,0,1},{1,1,0},{1,1,1},{1,1,2},
                              {1,2,1},{1,2,2},{2,0,2},{2,1,1},{2,2,0},{2,2,1},{2,2,2}};

__device__ __forceinline__ short f2bf(float f) {   // f32 -> bf16 (RNE)
  unsigned u = __float_as_uint(f);
  unsigned r = u + 0x7FFFu + ((u >> 16) & 1u);
  return (short)(r >> 16);
}

// ---------------- on-device Wigner 3j (exact replica of reference) ----------------
__device__ double dfact(int n){ double r=1.0; for(int i=2;i<=n;++i) r*=(double)i; return r; }

__device__ double cg_coef(int j1,int m1,int j2,int m2,int j3,int m3){
  if (m1+m2 != m3) return 0.0;
  int kmin = max(0, max(j2-j3-m1, j1-j3+m2));
  int kmax = min(j1+j2-j3, min(j1-m1, j2+m2));
  if (kmax < kmin) return 0.0;
  double pref = sqrt((2.0*j3+1.0)*dfact(j3+j1-j2)*dfact(j3-j1+j2)*dfact(j1+j2-j3)/dfact(j1+j2+j3+1));
  pref *= sqrt(dfact(j3+m3)*dfact(j3-m3)*dfact(j1-m1)*dfact(j1+m1)*dfact(j2-m2)*dfact(j2+m2));
  double s = 0.0;
  for (int k=kmin;k<=kmax;++k){
    double d = dfact(k)*dfact(j1+j2-j3-k)*dfact(j1-m1-k)*dfact(j2+m2-k)*dfact(j3-j2+m1+k)*dfact(j3-j1-m2+k);
    s += ((k&1)? -1.0:1.0)/d;
  }
  return pref*s;
}

__device__ void buildQ(int l, double (*qr)[5], double (*qi)[5]){
  const double is2 = 0.70710678118654752440;
  for (int a=0;a<5;++a) for(int b=0;b<5;++b){ qr[a][b]=0.0; qi[a][b]=0.0; }
  for (int m=-l; m<0; ++m){
    qr[l+m][l-m] = is2;
    qi[l+m][l+m] = -is2;
  }
  qr[l][l] = 1.0;
  for (int m=1; m<=l; ++m){
    double sgn = (m & 1) ? -1.0 : 1.0;
    qr[l+m][l+m] = sgn*is2;
    qi[l+m][l-m] = sgn*is2;
  }
  if (l == 1) {
    for (int a=0;a<5;++a) for(int b=0;b<5;++b){ double r=qr[a][b], im=qi[a][b]; qr[a][b]=im; qi[a][b]=-r; }
  } else if (l == 2) {
    for (int a=0;a<5;++a) for(int b=0;b<5;++b){ qr[a][b]=-qr[a][b]; qi[a][b]=-qi[a][b]; }
  }
}

__global__ __launch_bounds__(128) void w3j_kernel(float* __restrict__ w3j) {
  int kid = blockIdx.x;
  int l1 = KL[kid][0], l2 = KL[kid][1], l3 = KL[kid][2];
  int d1 = 2*l1+1, d2 = 2*l2+1, d3 = 2*l3+1;
  int n = d1*d2*d3;
  int t = threadIdx.x;
  __shared__ double sqr[3][5][5], sqi[3][5][5];
  __shared__ double sC[25];
  __shared__ double red[128], red2[128];

  if (t < 3) {
    int l = (t==0)?l1:(t==1)?l2:l3;
    buildQ(l, sqr[t], sqi[t]);
  }
  if (t < d1*d2) {
    int a = t/d2, b = t - a*d2;
    int m1 = a-l1, m2 = b-l2, m3 = m1+m2;
    sC[a*5+b] = (m3 >= -l3 && m3 <= l3) ? cg_coef(l1,m1,l2,m2,l3,m3) : 0.0;
  }
  __syncthreads();

  double ar = 0.0, ai = 0.0;
  int i=0, j=0, k=0;
  if (t < n) {
    i = t/(d2*d3); int r = t - i*d2*d3; j = r/d3; k = r - j*d3;
    for (int a=0;a<d1;++a) for (int b=0;b<d2;++b) {
      double cv = sC[a*5+b];
      if (cv == 0.0) continue;
      int c = a + b - l1 - l2 + l3;
      if (c < 0 || c >= d3) continue;
      double q1r=sqr[0][a][i], q1i=sqi[0][a][i];
      double q2r=sqr[1][b][j], q2i=sqi[1][b][j];
      double q3r=sqr[2][c][k], q3i=sqi[2][c][k];
      double tr = q1r*q2r - q1i*q2i;
      double ti = q1r*q2i + q1i*q2r;
      double ur = tr*q3r + ti*q3i;
      double ui = ti*q3r - tr*q3i;
      ar += ur*cv; ai += ui*cv;
    }
  }
  red[t]  = (t<n) ? fabs(ar) : 0.0;
  red2[t] = (t<n) ? fabs(ai) : 0.0;
  __syncthreads();
  for (int s=64; s>0; s>>=1) {
    if (t < s) { red[t] += red[t+s]; red2[t] += red2[t+s]; }
    __syncthreads();
  }
  bool use_re = red[0] > red2[0];
  double v = use_re ? ar : ai;
  __syncthreads();
  red[t] = (t<n) ? v*v : 0.0;
  __syncthreads();
  for (int s=64; s>0; s>>=1) {
    if (t < s) red[t] += red[t+s];
    __syncthreads();
  }
  double inv = 1.0/sqrt(red[0]);
  if (t < n) w3j[kid*125 + (i*d2+j)*d3 + k] = (float)(v*inv);
}

// ---------------- W2 transpose -> bf16: W2Tb[col][h] = bf16(W2[h][col]) ----------------
__global__ void w2t_kernel(const float* __restrict__ W2, short* __restrict__ W2Tb) {
  int idx = blockIdx.x*256 + threadIdx.x;
  if (idx < 64*WDIM) {
    int c = idx >> 6, h = idx & 63;
    W2Tb[idx] = f2bf(W2[h*WDIM + c]);
  }
}

// ---------------- tp compute (templated: compile-time bounds -> full unroll) ----------------
template<int KEY,int MU,int D1,int D2,int D3,int SLA,int SLB>
__device__ __forceinline__ void tp_compute_t(int t, const float* __restrict__ s_w3j,
    float (*s_xj)[84], float (*s_sh)[12], float (*s_tp)[84])
{
  constexpr int MD = MU * D3;
  #pragma unroll
  for (int it = 0; it < MD/4; ++it) {          // 64*MD/256 == MD/4 exactly (all paths)
    int idx = it*256 + t;
    int ee = idx / MD, r = idx - ee*MD;
    int u = r / D3, kk = r - u*D3;
    const float* cg = s_w3j + KEY*125 + kk;
    float s = 0.f;
    #pragma unroll
    for (int i = 0; i < D1; ++i) {
      float xa = s_xj[ee][SLA + u*D1 + i];
      #pragma unroll
      for (int jj = 0; jj < D2; ++jj)
        s = fmaf(xa * s_sh[ee][SLB + jj], cg[(i*D2 + jj)*D3], s);
    }
    s_tp[ee][r] = s;
  }
}

// ---------------- fused radial-MLP(MFMA) + tensor-product + scatter ----------------
// block = 256 threads = 4 waves, 64 edges; wave w owns edges w*16..w*16+15 (M=16).
// GEMM: w[64 edges][1184 cols] = act(64x64) @ W2Tb^T, bf16 MFMA 16x16x32, b2 in C-init.
// A-frag: lane holds act[wv*16 + (ln&15)][8*(ln>>4)+j]  (loop-invariant!)
// B-frag: lane holds W2Tb[cb + (ln&15)][8*(ln>>4)+j]    (B^T-row layout, m92-verified)
// C-frag: row(edge) = (ln>>4)*4+reg, col = ln&15        (m89-verified)
__global__ __launch_bounds__(256, 2) void edge_kernel(
  const float* __restrict__ x, const int* __restrict__ eidx,
  const float* __restrict__ shg, const float* __restrict__ rbf,
  const float* __restrict__ W1, const float* __restrict__ b1,
  const short* __restrict__ W2Tb, const float* __restrict__ b2,
  const float* __restrict__ w3j, float* __restrict__ m_i, int E)
{
  __shared__ __align__(16) short s_act[64][72];   // bf16 bits, pad 72 (bank-stagger)
  __shared__ float s_xj[64][84];
  __shared__ float s_sh[64][12];
  __shared__ float s_tp[64][84];
  __shared__ float s_w3j[14*125];                 // 7 KB: w3j staged to LDS
  int t = threadIdx.x;
  int e0 = blockIdx.x * 64;

  for (int idx = t; idx < 14*125; idx += 256) s_w3j[idx] = w3j[idx];
  for (int idx = t; idx < 64*84; idx += 256) {
    int e = idx/84, d = idx - e*84;
    int ge = e0 + e;
    int j = (ge < E) ? eidx[E + ge] : 0;
    s_xj[e][d] = x[j*84 + d];
  }
  for (int idx = t; idx < 64*9; idx += 256) {
    int e = idx/9, d = idx - e*9;
    int ge = min(e0 + e, E-1);
    s_sh[e][d] = shg[ge*9 + d];
  }
  for (int idx = t; idx < 64*64; idx += 256) {
    int e = idx >> 6, h = idx & 63;
    int ge = min(e0 + e, E-1);
    float s = b1[h];
    const float* r = rbf + ge*16;
    #pragma unroll
    for (int q = 0; q < 16; ++q) s = fmaf(r[q], W1[q*64 + h], s);
    s = s / (1.f + expf(-s));                   // silu
    s_act[e][h] = f2bf(s);
  }
  __syncthreads();

  int wv = t >> 6, ln = t & 63;
  int col16 = ln & 15, kg = ln >> 4;
  int wrow = wv*16 + kg*4;                       // first of this lane's 4 C-row edges

  // loop-invariant A fragments (this wave's 16 edges, K=64 in two 32-chunks)
  bf16x8 a0 = *(const bf16x8*)&s_act[wv*16 + col16][kg*8];
  bf16x8 a1 = *(const bf16x8*)&s_act[wv*16 + col16][32 + kg*8];

  float acc0[4][1] = {};
  float acc1[4][3] = {};
  float acc2[4][3] = {};
  float acc3[4][5] = {};

#define PROC(WOFF, NTILES, D3, UPT, LOGMV, ACC)                                   \
  {                                                                                \
    _Pragma("unroll")                                                              \
    for (int nt = 0; nt < NTILES; ++nt) {                                          \
      int cb = WOFF + nt*16;                                                       \
      bf16x8 bb0 = *(const bf16x8*)&W2Tb[(cb + col16)*64 + kg*8];                  \
      bf16x8 bb1 = *(const bf16x8*)&W2Tb[(cb + col16)*64 + 32 + kg*8];             \
      float b2v = b2[cb + col16];                                                  \
      f32x4 c = {b2v, b2v, b2v, b2v};                                              \
      c = __builtin_amdgcn_mfma_f32_16x16x32_bf16(a0, bb0, c, 0, 0, 0);            \
      c = __builtin_amdgcn_mfma_f32_16x16x32_bf16(a1, bb1, c, 0, 0, 0);            \
      int u = nt*UPT + (col16 >> LOGMV);                                           \
      _Pragma("unroll")                                                            \
      for (int r = 0; r < 4; ++r) {                                                \
        const float* tpp = &s_tp[wrow + r][u*D3];                                  \
        float cf = c[r];                                                           \
        _Pragma("unroll")                                                          \
        for (int k = 0; k < D3; ++k) ACC[r][k] = fmaf(tpp[k], cf, ACC[r][k]);      \
      }                                                                            \
    }                                                                              \
  }

#define PATH(KEY,MU,D1,D2,D3,SLA,SLB, PROCCALL)                                    \
  __syncthreads();                                                                 \
  tp_compute_t<KEY,MU,D1,D2,D3,SLA,SLB>(t, s_w3j, s_xj, s_sh, s_tp);               \
  __syncthreads();                                                                 \
  PROCCALL

  PATH(0, 16,1,1,1, 0,0,  PROC(0,    16, 1, 1, 4, acc0))   // (0,0,0)
  PATH(1, 16,1,3,3, 0,1,  PROC(256,   8, 3, 2, 3, acc1))   // (0,1,1)
  PATH(2, 16,1,5,5, 0,4,  PROC(384,   4, 5, 4, 2, acc3))   // (0,2,3)
  PATH(3,  8,3,1,3, 16,0, PROC(448,   4, 3, 2, 3, acc1))   // (1,0,1)
  PATH(4,  8,3,3,1, 16,1, PROC(512,   8, 1, 1, 4, acc0))   // (1,1,0)
  PATH(5,  8,3,3,3, 16,1, PROC(640,   4, 3, 2, 3, acc2))   // (1,1,2)
  PATH(6,  8,3,3,5, 16,1, PROC(704,   2, 5, 4, 2, acc3))   // (1,1,3)
  PATH(7,  8,3,5,3, 16,4, PROC(736,   4, 3, 2, 3, acc1))   // (1,2,1)
  PATH(3,  8,3,1,3, 40,0, PROC(800,   4, 3, 2, 3, acc2))   // (2,0,2)
  PATH(5,  8,3,3,3, 40,1, PROC(864,   4, 3, 2, 3, acc1))   // (2,1,1)
  PATH(7,  8,3,5,3, 40,4, PROC(928,   4, 3, 2, 3, acc2))   // (2,2,2)
  PATH(8,  8,3,5,5, 40,4, PROC(992,   2, 5, 4, 2, acc3))   // (2,2,3)
  PATH(9,  4,5,1,5, 64,0, PROC(1024,  1, 5, 4, 2, acc3))   // (3,0,3)
  PATH(10, 4,5,3,3, 64,1, PROC(1040,  2, 3, 2, 3, acc1))   // (3,1,1)
  PATH(11, 4,5,5,1, 64,4, PROC(1072,  4, 1, 1, 4, acc0))   // (3,2,0)
  PATH(12, 4,5,5,3, 64,4, PROC(1136,  2, 3, 2, 3, acc2))   // (3,2,2)
  PATH(13, 4,5,5,5, 64,4, PROC(1168,  1, 5, 4, 2, acc3))   // (3,2,3)

  // combine u-subgroups across lanes sharing the same v (linear, deferred to end):
  // mv=8 -> lanes c and c^8; mv=4 -> c, c^4, c^8, c^12
  #pragma unroll
  for (int r = 0; r < 4; ++r) {
    #pragma unroll
    for (int k = 0; k < 3; ++k) {
      acc1[r][k] += __shfl_xor(acc1[r][k], 8);
      acc2[r][k] += __shfl_xor(acc2[r][k], 8);
    }
    #pragma unroll
    for (int k = 0; k < 5; ++k) {
      float v = acc3[r][k];
      v += __shfl_xor(v, 8);
      v += __shfl_xor(v, 4);
      acc3[r][k] = v;
    }
  }

  const float FAN0 = 0.18898223650461363f;   // 1/sqrt(28)
  const float FAN1 = 0.15075567228888181f;   // 1/sqrt(44)
  const float FAN2 = 0.18898223650461363f;   // 1/sqrt(28)
  const float FAN3 = 0.15811388300841897f;   // 1/sqrt(40)
  #pragma unroll
  for (int r = 0; r < 4; ++r) {
    int ge = e0 + wrow + r;
    if (ge >= E) continue;
    int ni = eidx[ge];                         // edge_index[0] = destination
    float* mrow = m_i + ni*84;
    atomicAdd(&mrow[col16], acc0[r][0]*FAN0);
    if (col16 < 8) {
      #pragma unroll
      for (int k = 0; k < 3; ++k) atomicAdd(&mrow[16 + col16*3 + k], acc1[r][k]*FAN1);
      #pragma unroll
      for (int k = 0; k < 3; ++k) atomicAdd(&mrow[40 + col16*3 + k], acc2[r][k]*FAN2);
    }
    if (col16 < 4) {
      #pragma unroll
      for (int k = 0; k < 5; ++k) atomicAdd(&mrow[64 + col16*5 + k], acc3[r][k]*FAN3);
    }
  }
#undef PROC
#undef PATH
}

// ---------------- block-diagonal o3_linear helpers ----------------
__device__ float o3lin_hh(const float* v, const float* w, int d) {
  float s = 0.f;
  if (d < 16) {
    #pragma unroll
    for (int u = 0; u < 16; ++u) s = fmaf(v[u], w[u*16 + d], s);
    return s * 0.25f;
  } else if (d < 40) {
    int loc = d-16, vv = loc/3, kk = loc - vv*3;
    #pragma unroll
    for (int u = 0; u < 8; ++u) s = fmaf(v[16 + u*3 + kk], w[256 + u*8 + vv], s);
    return s * 0.35355339059327373f;
  } else if (d < 64) {
    int loc = d-40, vv = loc/3, kk = loc - vv*3;
    #pragma unroll
    for (int u = 0; u < 8; ++u) s = fmaf(v[40 + u*3 + kk], w[320 + u*8 + vv], s);
    return s * 0.35355339059327373f;
  } else {
    int loc = d-64, vv = loc/5, kk = loc - vv*5;
    #pragma unroll
    for (int u = 0; u < 4; ++u) s = fmaf(v[64 + u*5 + kk], w[384 + u*4 + vv], s);
    return s * 0.5f;
  }
}

__device__ float o3lin_pre(const float* v, const float* w, int d) {
  float s = 0.f;
  if (d < 16) {
    #pragma unroll
    for (int u = 0; u < 16; ++u) s = fmaf(v[u], w[u*16 + d], s);
    return s * 0.25f;
  } else if (d < 36) {
    int vv = d - 16;
    #pragma unroll
    for (int u = 0; u < 16; ++u) s = fmaf(v[u], w[256 + u*20 + vv], s);
    return s * 0.25f;
  } else if (d < 60) {
    int loc = d-36, vv = loc/3, kk = loc - vv*3;
    #pragma unroll
    for (int u = 0; u < 8; ++u) s = fmaf(v[16 + u*3 + kk], w[576 + u*8 + vv], s);
    return s * 0.35355339059327373f;
  } else if (d < 84) {
    int loc = d-60, vv = loc/3, kk = loc - vv*3;
    #pragma unroll
    for (int u = 0; u < 8; ++u) s = fmaf(v[40 + u*3 + kk], w[640 + u*8 + vv], s);
    return s * 0.35355339059327373f;
  } else {
    int loc = d-84, vv = loc/5, kk = loc - vv*5;
    #pragma unroll
    for (int u = 0; u < 4; ++u) s = fmaf(v[64 + u*5 + kk], w[704 + u*4 + vv], s);
    return s * 0.5f;
  }
}

// ---------------- h1 = x + lin_res(m_i); accumulate bn stats ----------------
__global__ __launch_bounds__(256) void node_res_kernel(
  const float* __restrict__ x, const float* __restrict__ m_i,
  const float* __restrict__ lw, float* __restrict__ h1,
  float* __restrict__ stats, int N)
{
  __shared__ float s_m[4][84];
  __shared__ float s_sum[16];
  __shared__ float s_sq[36];
  int t = threadIdx.x;
  int n0 = blockIdx.x*4;
  if (t < 16) s_sum[t] = 0.f;
  if (t < 36) s_sq[t] = 0.f;
  for (int idx = t; idx < 4*84; idx += 256) {
    int e = idx/84, d = idx - e*84;
    int n = n0 + e;
    s_m[e][d] = (n < N) ? m_i[n*84 + d] : 0.f;
  }
  __syncthreads();
  int w = t >> 6, lane = t & 63;
  int n = n0 + w;
  for (int rep = 0; rep < 2; ++rep) {
    int d = lane + rep*64;
    if (d < 84 && n < N) {
      float v = x[n*84 + d] + o3lin_hh(s_m[w], lw, d);
      h1[n*84 + d] = v;
      if (d < 16) {
        atomicAdd(&s_sum[d], v);
        atomicAdd(&s_sq[d], v*v);
      } else {
        int ch = (d < 40) ? 16 + (d-16)/3 : (d < 64) ? 24 + (d-40)/3 : 32 + (d-64)/5;
        atomicAdd(&s_sq[ch], v*v);
      }
    }
  }
  __syncthreads();
  if (t < 16) atomicAdd(&stats[t], s_sum[t]);
  if (t < 36) atomicAdd(&stats[16 + t], s_sq[t]);
}

// ---------------- batchnorm finalize ----------------
__global__ void bn_finalize_kernel(const float* __restrict__ stats,
                                   const float* __restrict__ bnw,
                                   const float* __restrict__ bnb,
                                   float* __restrict__ scsh, int N)
{
  int t = threadIdx.x;
  if (t >= 36) return;
  float q = stats[16 + t];
  float scale, shift = 0.f;
  if (t < 16) {
    float mean = stats[t] / (float)N;
    float var  = q / (float)N - mean*mean;
    scale = bnw[t] / sqrtf(var + 1e-5f);
    shift = bnb[t] - mean*scale;
  } else {
    float dd = (t < 32) ? 3.f : 5.f;
    float var = q / ((float)N * dd);
    scale = bnw[t] / sqrtf(var + 1e-5f);
  }
  scsh[t] = scale;
  scsh[36 + t] = shift;
}

// ---------------- bn apply + pre_gate + gate + post_gate ----------------
__global__ __launch_bounds__(256) void node_out_kernel(
  const float* __restrict__ h1, const float* __restrict__ scsh,
  const float* __restrict__ wpre, const float* __restrict__ wpost,
  float* __restrict__ out, int N)
{
  __shared__ float s_y[4][84];
  __shared__ float s_p[4][104];
  __shared__ float s_g[4][84];
  int t = threadIdx.x;
  int n0 = blockIdx.x*4;
  for (int idx = t; idx < 4*84; idx += 256) {
    int e = idx/84, d = idx - e*84;
    int n = n0 + e;
    float v = (n < N) ? h1[n*84 + d] : 0.f;
    int ch = (d < 16) ? d : (d < 40) ? 16 + (d-16)/3 : (d < 64) ? 24 + (d-40)/3 : 32 + (d-64)/5;
    s_y[e][d] = v*scsh[ch] + scsh[36 + ch];
  }
  __syncthreads();
  int w = t >> 6, lane = t & 63;
  for (int rep = 0; rep < 2; ++rep) {
    int d = lane + rep*64;
    if (d < 104) s_p[w][d] = o3lin_pre(s_y[w], wpre, d);
  }
  __syncthreads();
  for (int rep = 0; rep < 2; ++rep) {
    int d = lane + rep*64;
    if (d < 84) {
      float v;
      if (d < 16)      { float sv = s_p[w][d]; v = sv / (1.f + expf(-sv)); }
      else if (d < 40) { int loc = d-16; v = s_p[w][36 + loc] / (1.f + expf(-s_p[w][16 + loc/3])); }
      else if (d < 64) { int loc = d-40; v = s_p[w][60 + loc] / (1.f + expf(-s_p[w][24 + loc/3])); }
      else             { int loc = d-64; v = s_p[w][84 + loc] / (1.f + expf(-s_p[w][32 + loc/5])); }
      s_g[w][d] = v;
    }
  }
  __syncthreads();
  int n = n0 + w;
  for (int rep = 0; rep < 2; ++rep) {
    int d = lane + rep*64;
    if (d < 84 && n < N) out[n*84 + d] = o3lin_hh(s_g[w], wpost, d);
  }
}

// ---------------- launch ----------------
extern "C" void kernel_launch(void* const* d_in, const int* in_sizes, int n_in,
                              void* d_out, int out_size, void* d_ws, size_t ws_size,
                              hipStream_t stream)
{
  const float* x    = (const float*)d_in[0];
  const int*   eidx = (const int*)d_in[1];
  const float* shg  = (const float*)d_in[2];
  const float* rbf  = (const float*)d_in[3];
  const float* W1   = (const float*)d_in[4];
  const float* b1   = (const float*)d_in[5];
  const float* W2   = (const float*)d_in[6];
  const float* b2   = (const float*)d_in[7];
  const float* lrw  = (const float*)d_in[8];
  const float* prw  = (const float*)d_in[9];
  const float* pgw  = (const float*)d_in[10];
  const float* bnw  = (const float*)d_in[11];
  const float* bnb  = (const float*)d_in[12];
  int N = in_sizes[0] / 84;
  int E = in_sizes[1] / 2;

  // ws layout (floats): m_i[N*84] | stats[64] | scsh[80] | h1[N*84] | w3j[1750] | W2Tb(bf16)
  float* ws    = (float*)d_ws;
  float* m_i   = ws;
  float* stats = ws + (size_t)N*84;
  float* scsh  = stats + 64;
  float* h1    = scsh + 80;
  float* w3j   = h1 + (size_t)N*84;
  short* W2Tb  = (short*)(w3j + 14*125);

  hipMemsetAsync(m_i, 0, ((size_t)N*84 + 64)*sizeof(float), stream);
  w3j_kernel<<<14, 128, 0, stream>>>(w3j);
  w2t_kernel<<<(64*WDIM + 255)/256, 256, 0, stream>>>(W2, W2Tb);
  edge_kernel<<<(E + 63)/64, 256, 0, stream>>>(x, eidx, shg, rbf, W1, b1, W2Tb, b2, w3j, m_i, E);
  node_res_kernel<<<(N + 3)/4, 256, 0, stream>>>(x, m_i, lrw, h1, stats, N);
  bn_finalize_kernel<<<1, 64, 0, stream>>>(stats, bnw, bnb, scsh, N);
  node_out_kernel<<<(N + 3)/4, 256, 0, stream>>>(h1, scsh, prw, pgw, (float*)d_out, N);
}